// Round 4
// baseline (35.988 us; speedup 1.0000x reference)
//
#include <hip/hip_runtime.h>

namespace {
constexpr int kM = 4, kJ = 2, kI = 3, kL = 2, kW = 9;
constexpr float kInvLn2 = 1.4426950408889634f;

typedef float v2f __attribute__((ext_vector_type(2)));  // -> v_pk_*_f32

__device__ __forceinline__ float fexp2(float x) { return __builtin_amdgcn_exp2f(x); }

// dp layout (80 floats), per m (18 floats at m*18), j-packed {j0,j1} pairs:
//   [A, B0, B1, w0, w1, C00, C01, C10, C11]  (A/B/w pre-scaled by 1/ln2)
// D[m][l] at 72 + m*2 + l.
__global__ void prep_kernel(const float* __restrict__ constants,
                            const float* __restrict__ gammas,
                            const float* __restrict__ W_body,
                            const float* __restrict__ b_body,
                            const float* __restrict__ W_head,
                            const float* __restrict__ b_head,
                            float* __restrict__ dp) {
  const int t = threadIdx.x;
  if (t < 8) {
    const int mj = t, m = t >> 1, j = t & 1;
    const float g0 = fminf(fmaxf(gammas[mj * kL + 0], 0.f), 1.f);
    const float g1 = fminf(fmaxf(gammas[mj * kL + 1], 0.f), 1.f);
    const float w0 = 1.f - g0, w1 = 1.f - g1;
    const float c0 = constants[mj * kL + 0], c1 = constants[mj * kL + 1];
    const float gavg = 0.5f * (g0 + g1);
    float* base = dp + m * 18;
    base[0 * 2 + j] = (w0 * c0 * c0 + w1 * c1 * c1) * kInvLn2;  // A
    base[1 * 2 + j] = -2.f * w0 * c0 * kInvLn2;                 // B0
    base[2 * 2 + j] = -2.f * w1 * c1 * kInvLn2;                 // B1
    base[3 * 2 + j] = w0 * kInvLn2;                             // w0
    base[4 * 2 + j] = w1 * kInvLn2;                             // w1
    for (int l = 0; l < kL; ++l)
      for (int lp = 0; lp < kL; ++lp) {
        float acc = 0.f;
        for (int i = 0; i < kI; ++i)
          acc += W_head[(m * kL + l) * kI + i] * W_body[(mj * kI + i) * kL + lp];
        base[(5 + l * kL + lp) * 2 + j] = gavg * acc;           // C[l][lp]
      }
  } else if (t < 12) {
    const int m = t - 8;
    for (int l = 0; l < kL; ++l) {
      float d = b_head[m * kL + l];
      for (int j = 0; j < kJ; ++j) {
        const int mj = m * kJ + j;
        const float g0 = fminf(fmaxf(gammas[mj * kL + 0], 0.f), 1.f);
        const float g1 = fminf(fmaxf(gammas[mj * kL + 1], 0.f), 1.f);
        const float gavg = 0.5f * (g0 + g1);
        float acc = 0.f;
        for (int i = 0; i < kI; ++i)
          acc += W_head[(m * kL + l) * kI + i] * b_body[mj * kI + i];
        d += gavg * acc;
      }
      dp[72 + m * kL + l] = d;
    }
  }
}

__global__ __launch_bounds__(128, 6) void algelogic_main(
    const float* __restrict__ state, const float* __restrict__ dp,
    float* __restrict__ out) {
  __shared__ float sdp[80];
  const int t = threadIdx.x;

  // thin LDS fill: one coalesced load + ds_write (no dependent chain)
  if (t < 80) sdp[t] = dp[t];

  const int b = blockIdx.x * 128 + t;
  const float* srow = state + (size_t)b * (kW * kL);
  v2f sv[kW];
#pragma unroll
  for (int w = 0; w < kW; ++w) {
    const float2 v = *reinterpret_cast<const float2*>(srow + 2 * w);
    v2f s; s.x = v.x; s.y = v.y;
    sv[w] = s;
  }
  __syncthreads();

  float Cs = 0.f, X0 = 0.f, X1 = 0.f, K = 0.f;
#pragma unroll
  for (int m = 0; m < kM; ++m) {
    const v2f* pp = reinterpret_cast<const v2f*>(sdp + m * 18);
    const v2f A = pp[0], B0 = pp[1], B1 = pp[2], w0 = pp[3], w1 = pp[4];

    v2f msP[kW];
    v2f mn = {3.4e38f, 3.4e38f};
#pragma unroll
    for (int w = 0; w < kW; ++w) {
      const float s0w = sv[w].x, s1w = sv[w].y;
      // ms = A + s0*(B0 + w0*s0) + s1*(B1 + w1*s1)   (no squares needed)
      const v2f t0 = B0 + w0 * s0w;
      const v2f t1 = B1 + w1 * s1w;
      v2f v = A + t0 * s0w;
      v += t1 * s1w;
      msP[w] = v;
      mn = __builtin_elementwise_min(mn, v);
    }

    v2f psum = {0.f, 0.f}, pb0 = {0.f, 0.f}, pb1 = {0.f, 0.f}, pmq = {0.f, 0.f};
#pragma unroll
    for (int w = 0; w < kW; ++w) {
      const v2f d = mn - msP[w];          // <= 0, log2 units
      v2f e; e.x = fexp2(d.x); e.y = fexp2(d.y);
      psum += e;
      pb0 += e * sv[w].x;
      pb1 += e * sv[w].y;
      pmq += e * msP[w];                  // log2-scaled ms
    }

    v2f rinv;
    rinv.x = __builtin_amdgcn_rcpf(psum.x);
    rinv.y = __builtin_amdgcn_rcpf(psum.y);
    const v2f bb0 = pb0 * rinv, bb1 = pb1 * rinv;
    const v2f mqP = pmq * rinv;
    const float mq2 = mqP.x + mqP.y;      // sum over j (log2 units)
    const float conf = fexp2(-mq2);       // == exp(-match_quality)

    const v2f C00 = pp[5], C01 = pp[6], C10 = pp[7], C11 = pp[8];
    const v2f t0 = C00 * bb0 + C01 * bb1;
    const v2f t1 = C10 * bb0 + C11 * bb1;
    const float r0 = sdp[72 + m * 2 + 0] + t0.x + t0.y;
    const float r1 = sdp[72 + m * 2 + 1] + t1.x + t1.y;

    Cs += conf;
    X0 = fmaf(conf, r0, X0);
    X1 = fmaf(conf, r1, X1);
    K = fmaf(conf, fmaf(r0, r0, r1 * r1), K);
  }

  const float X02 = 2.f * X0, X12 = 2.f * X1;
  float* orow = out + (size_t)b * kW;
#pragma unroll
  for (int w = 0; w < kW; ++w) {
    const v2f q = sv[w] * sv[w];
    const float qs = q.x + q.y;
    // out = 2X0*s0 + 2X1*s1 - Cs*(s0^2+s1^2) - K
    orow[w] = fmaf(X02, sv[w].x, fmaf(X12, sv[w].y, fmaf(-Cs, qs, -K)));
  }
}
}  // namespace

extern "C" void kernel_launch(void* const* d_in, const int* in_sizes, int n_in,
                              void* d_out, int out_size, void* d_ws, size_t ws_size,
                              hipStream_t stream) {
  const float* state     = (const float*)d_in[0];
  const float* constants = (const float*)d_in[1];
  const float* gammas    = (const float*)d_in[2];
  const float* W_body    = (const float*)d_in[3];
  const float* b_body    = (const float*)d_in[4];
  const float* W_head    = (const float*)d_in[5];
  const float* b_head    = (const float*)d_in[6];
  float* out = (float*)d_out;
  float* dp  = (float*)d_ws;

  const int B = in_sizes[0] / (kW * kL);   // 1048576
  hipLaunchKernelGGL(prep_kernel, dim3(1), dim3(64), 0, stream,
                     constants, gammas, W_body, b_body, W_head, b_head, dp);
  hipLaunchKernelGGL(algelogic_main, dim3(B / 128), dim3(128), 0, stream,
                     state, dp, out);
}